// Round 11
// baseline (2186.209 us; speedup 1.0000x reference)
//
#include <hip/hip_runtime.h>

#define TT 512
#define HH 256
#define BB 128

typedef unsigned long long u64;

// 16 FMAs of two weight rows against one 16-wide h chunk (loads split 2+2
// float4 to cap live temps at 8 under the 64-VGPR budget).
__device__ __forceinline__ void dot2(const float* h, const float* wa_,
                                     const float* wb_, float& ra, float& rb) {
    float4 p0 = *(const float4*)(h);
    float4 p1 = *(const float4*)(h + 4);
    float a, b;
    a = wa_[0] * p0.x;                    b = wb_[0] * p0.x;
    a = __builtin_fmaf(wa_[1], p0.y, a);  b = __builtin_fmaf(wb_[1], p0.y, b);
    a = __builtin_fmaf(wa_[2], p0.z, a);  b = __builtin_fmaf(wb_[2], p0.z, b);
    a = __builtin_fmaf(wa_[3], p0.w, a);  b = __builtin_fmaf(wb_[3], p0.w, b);
    a = __builtin_fmaf(wa_[4], p1.x, a);  b = __builtin_fmaf(wb_[4], p1.x, b);
    a = __builtin_fmaf(wa_[5], p1.y, a);  b = __builtin_fmaf(wb_[5], p1.y, b);
    a = __builtin_fmaf(wa_[6], p1.z, a);  b = __builtin_fmaf(wb_[6], p1.z, b);
    a = __builtin_fmaf(wa_[7], p1.w, a);  b = __builtin_fmaf(wb_[7], p1.w, b);
    float4 p2 = *(const float4*)(h + 8);
    float4 p3 = *(const float4*)(h + 12);
    a = __builtin_fmaf(wa_[8],  p2.x, a); b = __builtin_fmaf(wb_[8],  p2.x, b);
    a = __builtin_fmaf(wa_[9],  p2.y, a); b = __builtin_fmaf(wb_[9],  p2.y, b);
    a = __builtin_fmaf(wa_[10], p2.z, a); b = __builtin_fmaf(wb_[10], p2.z, b);
    a = __builtin_fmaf(wa_[11], p2.w, a); b = __builtin_fmaf(wb_[11], p2.w, b);
    a = __builtin_fmaf(wa_[12], p3.x, a); b = __builtin_fmaf(wb_[12], p3.x, b);
    a = __builtin_fmaf(wa_[13], p3.y, a); b = __builtin_fmaf(wb_[13], p3.y, b);
    a = __builtin_fmaf(wa_[14], p3.z, a); b = __builtin_fmaf(wb_[14], p3.z, b);
    a = __builtin_fmaf(wa_[15], p3.w, a); b = __builtin_fmaf(wb_[15], p3.w, b);
    ra = a; rb = b;
}

// 256 wgs x 1024 threads, cooperative. Group g (= wg & 31) = wgs
// {g, g+32, ..., g+224}, batches 4g..4g+3, one batch per phase (4 phases/step,
// 1 barrier each). Member q = wg>>5 owns h elems [32q,32q+32).
// Lane layout: kc = lane&15 (K-chunk), rs = lane>>4 = GATE index; wave w owns
// elems 2w, 2w+1 (all 4 gates) -> after kc-butterfly + 8-shfl gather the full
// cell update runs in-wave (lanes 0-1), no gates LDS, no second barrier.
// Import pipelined 4-deep: batch k's load issued 2 phases after its publish,
// consumed 2 phases later (RTT hidden); pendE (phases 0/2) / pendO (1/3).
// Exchange: epoch-tagged {epoch,h} 8B agent-scope relaxed atomics, 2-slot
// parity (race-free: max intra-group skew is 1 step).
__global__ __launch_bounds__(1024)
__attribute__((amdgpu_waves_per_eu(4, 4)))
void lstm_coop(
    const float* __restrict__ x,      // [B,T]
    const float* __restrict__ W_ih,   // [1024]
    const float* __restrict__ W_hh,   // [1024,256]
    const float* __restrict__ b_ih,   // [1024]
    const float* __restrict__ b_hh,   // [1024]
    const float* __restrict__ W1,     // [128,256]
    const float* __restrict__ b1,     // [128]
    const float* __restrict__ W2,     // [128]
    const float* __restrict__ b2,     // [1]
    float* __restrict__ out,          // [B]
    u64* __restrict__ hpair)          // [2][BB][HH] {epoch,h}
{
    const int wg  = blockIdx.x;
    const int g   = wg & 31;
    const int q   = wg >> 5;
    const int tid = threadIdx.x;
    const int b0  = 4 * g;

    __shared__ float x_lds[4][TT];        // 8 KB
    __shared__ float h_lds[4][320];       // 5 KB (stride 20 per 16-chunk)
    __shared__ float cc[32][8];           // 1 KB  (4x wih + 4x bias per elem)
    __shared__ float red_lds[4][128];     // 2 KB

    const int w    = tid >> 6;        // wave 0..15 -> elems 2w, 2w+1
    const int lane = tid & 63;
    const int kc   = lane & 15;       // K-chunk of 16
    const int rs   = lane >> 4;       // GATE index 0..3
    const int RA = rs * HH + q * 32 + 2 * w;       // gate rs, elem 2w
    const int RB = RA + 1;                         // gate rs, elem 2w+1

    // resident weights: 2 rows x 16 K = 32 VGPRs
    float wa[16], wb[16];
    {
        const float4* pa = reinterpret_cast<const float4*>(W_hh + (size_t)RA * HH + 16 * kc);
        const float4* pb = reinterpret_cast<const float4*>(W_hh + (size_t)RB * HH + 16 * kc);
        #pragma unroll
        for (int k = 0; k < 4; ++k) {
            float4 va = pa[k], vb = pb[k];
            wa[4*k+0] = va.x; wa[4*k+1] = va.y; wa[4*k+2] = va.z; wa[4*k+3] = va.w;
            wb[4*k+0] = vb.x; wb[4*k+1] = vb.y; wb[4*k+2] = vb.z; wb[4*k+3] = vb.w;
        }
    }
    #pragma unroll
    for (int k = 0; k < 16; ++k) {
        asm volatile("" : "+v"(wa[k]));
        asm volatile("" : "+v"(wb[k]));
    }

    // stage x for 4 batches
    #pragma unroll
    for (int u = 0; u < 2; ++u) {
        int idx = tid + u * 1024;
        int m = idx >> 9, j = idx & 511;
        x_lds[m][j] = x[(size_t)(b0 + m) * TT + j];
    }
    // cell constants per elem l: 4x wih + 4x bias
    if (tid < 32) {
        #pragma unroll
        for (int G = 0; G < 4; ++G) {
            const int R = G * HH + q * 32 + tid;
            cc[tid][G]     = W_ih[R];
            cc[tid][4 + G] = b_ih[R] + b_hh[R];
        }
    }

    // cell states: wave-local, lanes 0/1 of each wave (elem 2w / 2w+1), 4 batches
    float c0A = 0.f, c0B = 0.f, c1A = 0.f, c1B = 0.f;
    float c2A = 0.f, c2B = 0.f, c3A = 0.f, c3B = 0.f;
    // pipelined import regs: {epoch,h}; init 0 == epoch0/h=0 == h(0)
    u64 pendE = 0, pendO = 0;
    __syncthreads();

// phase K: consume PEND (batch K, epoch t) -> h_lds[K]; barrier; re-issue PEND
// for batch (K+2)&3 at slot NSLOT (2-phase flight); dot; butterfly+gather;
// cell+publish (lanes 0-1).
#define PHASE(K, PEND, CRA, CRB, NSLOT)                                         \
    do {                                                                        \
        if (tid < 256) {                                                        \
            const u64* sp_ = &hpair[((size_t)(t & 1) * BB + (b0 + K)) * HH + tid]; \
            u64 v_ = PEND;                                                      \
            while ((unsigned)(v_ >> 32) < (unsigned)t)                          \
                v_ = __hip_atomic_load(sp_, __ATOMIC_RELAXED, __HIP_MEMORY_SCOPE_AGENT); \
            h_lds[K][20 * (tid >> 4) + (tid & 15)] = __uint_as_float((unsigned)v_); \
        }                                                                       \
        __syncthreads();                                                        \
        if (tid < 256) {                                                        \
            PEND = __hip_atomic_load(                                           \
                &hpair[((size_t)(NSLOT) * BB + (b0 + ((K + 2) & 3))) * HH + tid], \
                __ATOMIC_RELAXED, __HIP_MEMORY_SCOPE_AGENT);                    \
        }                                                                       \
        float aA, aB;                                                           \
        dot2(&h_lds[K][20 * kc], wa, wb, aA, aB);                               \
        aA += __shfl_xor(aA, 1, 64);  aB += __shfl_xor(aB, 1, 64);              \
        aA += __shfl_xor(aA, 2, 64);  aB += __shfl_xor(aB, 2, 64);              \
        aA += __shfl_xor(aA, 4, 64);  aB += __shfl_xor(aB, 4, 64);              \
        aA += __shfl_xor(aA, 8, 64);  aB += __shfl_xor(aB, 8, 64);              \
        float giA = __shfl(aA, 0, 64),  gfA = __shfl(aA, 16, 64);               \
        float ggA = __shfl(aA, 32, 64), goA = __shfl(aA, 48, 64);               \
        float giB = __shfl(aB, 0, 64),  gfB = __shfl(aB, 16, 64);               \
        float ggB = __shfl(aB, 32, 64), goB = __shfl(aB, 48, 64);               \
        if (lane < 2) {                                                         \
            const int me = 2 * w + lane;                                        \
            float gi  = lane ? giB : giA;                                       \
            float gf  = lane ? gfB : gfA;                                       \
            float gg_ = lane ? ggB : ggA;                                       \
            float go  = lane ? goB : goA;                                       \
            const float xv = x_lds[K][t];                                       \
            gi  += __builtin_fmaf(xv, cc[me][0], cc[me][4]);                    \
            gf  += __builtin_fmaf(xv, cc[me][1], cc[me][5]);                    \
            gg_ += __builtin_fmaf(xv, cc[me][2], cc[me][6]);                    \
            go  += __builtin_fmaf(xv, cc[me][3], cc[me][7]);                    \
            gi  = __builtin_amdgcn_rcpf(1.f + __expf(-gi));                     \
            gf  = __builtin_amdgcn_rcpf(1.f + __expf(-gf));                     \
            go  = __builtin_amdgcn_rcpf(1.f + __expf(-go));                     \
            gg_ = 2.f * __builtin_amdgcn_rcpf(1.f + __expf(-2.f * gg_)) - 1.f;  \
            float cval = lane ? CRB : CRA;                                      \
            cval = __builtin_fmaf(gf, cval, gi * gg_);                          \
            float th = 2.f * __builtin_amdgcn_rcpf(1.f + __expf(-2.f * cval)) - 1.f; \
            float hn = go * th;                                                 \
            if (lane) CRB = cval; else CRA = cval;                              \
            u64 pk = ((u64)(unsigned)(t + 1) << 32) | (u64)__float_as_uint(hn); \
            __hip_atomic_store(&hpair[((size_t)((t + 1) & 1) * BB + (b0 + K)) * HH + (q * 32 + me)], \
                               pk, __ATOMIC_RELAXED, __HIP_MEMORY_SCOPE_AGENT); \
        }                                                                       \
    } while (0)

    for (int t = 0; t < TT; ++t) {
        PHASE(0, pendE, c0A, c0B, (t & 1));        // issues batch2, epoch t
        PHASE(1, pendO, c1A, c1B, (t & 1));        // issues batch3, epoch t
        PHASE(2, pendE, c2A, c2B, ((t + 1) & 1));  // issues batch0, epoch t+1
        PHASE(3, pendO, c3A, c3B, ((t + 1) & 1));  // issues batch1, epoch t+1
    }
#undef PHASE

    // ---- epilogue: q==0 imports final h (epoch TT, slot 0) and runs the MLP
    if (q == 0) {
        {
            const int m = tid >> 8, j = tid & 255;
            const u64* src = &hpair[((size_t)(TT & 1) * BB + (b0 + m)) * HH + j];
            u64 v = __hip_atomic_load(src, __ATOMIC_RELAXED, __HIP_MEMORY_SCOPE_AGENT);
            while ((unsigned)(v >> 32) < (unsigned)TT) {
                __builtin_amdgcn_s_sleep(1);
                v = __hip_atomic_load(src, __ATOMIC_RELAXED, __HIP_MEMORY_SCOPE_AGENT);
            }
            h_lds[m][20 * (j >> 4) + (j & 15)] = __uint_as_float((unsigned)v);
        }
        __syncthreads();
        if (tid < 512) {
            const int m = tid >> 7, j = tid & 127;
            const float4* w1p = reinterpret_cast<const float4*>(W1 + (size_t)j * HH);
            const float* hb = &h_lds[m][0];
            float s0 = 0.f, s1 = 0.f, s2 = 0.f, s3 = 0.f;
            #pragma unroll
            for (int k4 = 0; k4 < 64; ++k4) {
                float4 wv = w1p[k4];
                float4 hv = *(const float4*)(hb + 20 * (k4 >> 2) + 4 * (k4 & 3));
                s0 = __builtin_fmaf(wv.x, hv.x, s0);
                s1 = __builtin_fmaf(wv.y, hv.y, s1);
                s2 = __builtin_fmaf(wv.z, hv.z, s2);
                s3 = __builtin_fmaf(wv.w, hv.w, s3);
            }
            float rv = fmaxf((s0 + s1) + (s2 + s3) + b1[j], 0.f);
            red_lds[m][j] = rv * W2[j];
        }
        __syncthreads();
        if (tid < 4) {
            float y = b2[0];
            for (int k = 0; k < 128; ++k) y += red_lds[tid][k];
            out[b0 + tid] = y;
        }
    }
}

extern "C" void kernel_launch(void* const* d_in, const int* in_sizes, int n_in,
                              void* d_out, int out_size, void* d_ws, size_t ws_size,
                              hipStream_t stream) {
    const float* x    = (const float*)d_in[0];
    const float* W_ih = (const float*)d_in[1];
    const float* W_hh = (const float*)d_in[2];
    const float* b_ih = (const float*)d_in[3];
    const float* b_hh = (const float*)d_in[4];
    const float* W1   = (const float*)d_in[5];
    const float* b1   = (const float*)d_in[6];
    const float* W2   = (const float*)d_in[7];
    const float* b2   = (const float*)d_in[8];
    float* out  = (float*)d_out;

    u64* hpair = (u64*)d_ws;                    // [2][128][256] x 8B = 512 KB

    // epochs must be 0 at every call (d_ws persists across graph replays)
    (void)hipMemsetAsync(d_ws, 0, (size_t)2 * BB * HH * sizeof(u64), stream);

    void* args[] = {(void*)&x, (void*)&W_ih, (void*)&W_hh, (void*)&b_ih, (void*)&b_hh,
                    (void*)&W1, (void*)&b1, (void*)&W2, (void*)&b2,
                    (void*)&out, (void*)&hpair};
    (void)hipLaunchCooperativeKernel((void*)lstm_coop, dim3(256), dim3(1024), args, 0, stream);
}